// Round 1
// baseline (268.354 us; speedup 1.0000x reference)
//
#include <hip/hip_runtime.h>

#define BATCH 32
#define NDIM 512
#define LNUM 8
#define KDIM 8

// per-batch workspace layout (float offsets)
#define WS_PM     0        // int[512]  posmap: node -> pos in S, or -1
#define WS_S      512      // int[64]   S (padded with 0 beyond s)
#define WS_ACT    640      // float[512] active mask (0 if in wavelet set)
#define WS_W      1152     // float[64*64] W (right restricted to SxS; zero-padded)
#define WS_B2     5248     // float[64*64] B2 = W * A_SS * W^T
#define WS_C2     9344     // float[64*64] C2 = W^T * D_SS * W
#define WS_RA     13440    // float[64*512] RA[m][j] = sum_n W[m][n] A[S[n]][j]
#define WS_RD     46208    // float[64*512] RD[q][j] = sum_n W[n][q] D[S[n]][j]
#define WS_STRIDE 78976

__global__ __launch_bounds__(256) void k_setup(
    const float* __restrict__ A, const float* __restrict__ O,
    const int* __restrict__ indices, const int* __restrict__ wavelet,
    float* __restrict__ ws)
{
    const int b = blockIdx.x;
    const int tid = threadIdx.x;
    float* base = ws + (size_t)b * WS_STRIDE;
    int*   g_posmap = (int*)(base + WS_PM);
    int*   g_S      = (int*)(base + WS_S);
    float* g_act    = base + WS_ACT;
    float* g_W      = base + WS_W;
    float* g_B2     = base + WS_B2;
    float* g_C2     = base + WS_C2;

    __shared__ float Wl[64*64];
    __shared__ float ASS[64*64];
    __shared__ float Tm[64*64];
    __shared__ float tmp[KDIM*64];
    __shared__ int   idxsh[64];
    __shared__ int   Ssh[64];
    __shared__ int   pml[NDIM];
    __shared__ float actl[NDIM];
    __shared__ float actS[64];
    __shared__ int   prow[KDIM];
    __shared__ float Osh[KDIM*KDIM];
    __shared__ int   s_sh;

    for (int n = tid; n < NDIM; n += 256) { pml[n] = -1; actl[n] = 1.f; }
    if (tid < 64) idxsh[tid] = indices[b*64 + tid];
    __syncthreads();

    // build S (first-occurrence order) + posmap via wave-0 ballot
    if (tid < 64) {
        int n = idxsh[tid];
        bool first = true;
        for (int t = 0; t < tid; ++t) if (idxsh[t] == n) first = false;
        unsigned long long m = __ballot(first);
        int rank = __popcll(m & ((1ull << tid) - 1ull));
        if (first) { pml[n] = rank; Ssh[rank] = n; }
        if (tid == 0) s_sh = (int)__popcll(m);
    }
    if (tid >= 64 && tid < 64 + LNUM) {
        actl[wavelet[b*LNUM + (tid - 64)]] = 0.f;
    }
    __syncthreads();
    const int s = s_sh;
    if (tid < 64 && tid >= s) Ssh[tid] = 0;   // safe padding
    __syncthreads();

    for (int n = tid; n < NDIM; n += 256) { g_posmap[n] = pml[n]; g_act[n] = actl[n]; }
    if (tid < 64) { g_S[tid] = Ssh[tid]; actS[tid] = actl[Ssh[tid]]; }

    // W = I_s (zero padded)
    for (int t = tid; t < 4096; t += 256) {
        int rr = t >> 6, cc = t & 63;
        Wl[t] = (rr == cc && rr < s) ? 1.f : 0.f;
    }
    __syncthreads();

    // apply L layers: rows prow[i] of W <- sum_j O[i][j] * W[prow[j]]
    for (int l = 0; l < LNUM; ++l) {
        if (tid < KDIM) prow[tid] = pml[idxsh[l*KDIM + tid]];
        if (tid < KDIM*KDIM) Osh[tid] = O[((size_t)l*BATCH + b)*(KDIM*KDIM) + tid];
        __syncthreads();
        for (int t = tid; t < KDIM*64; t += 256) {
            int i = t >> 6, c = t & 63;
            float acc = 0.f;
            #pragma unroll
            for (int j = 0; j < KDIM; ++j) acc += Osh[i*KDIM + j] * Wl[prow[j]*64 + c];
            tmp[t] = acc;
        }
        __syncthreads();
        for (int t = tid; t < KDIM*64; t += 256) {
            int i = t >> 6, c = t & 63;
            Wl[prow[i]*64 + c] = tmp[t];
        }
        __syncthreads();
    }
    for (int t = tid; t < 4096; t += 256) g_W[t] = Wl[t];

    // gather A_SS = A[S, S]  (padded rows multiply W zeros -> exact)
    for (int t = tid; t < 4096; t += 256) {
        int n = t >> 6, mc = t & 63;
        ASS[t] = A[((size_t)b*NDIM + Ssh[n])*NDIM + Ssh[mc]];
    }
    __syncthreads();
    // Tm = W @ A_SS
    for (int t = tid; t < 4096; t += 256) {
        int q = t >> 6, mc = t & 63;
        float acc = 0.f;
        #pragma unroll 8
        for (int n = 0; n < 64; ++n) acc += Wl[q*64 + n] * ASS[n*64 + mc];
        Tm[t] = acc;
    }
    __syncthreads();
    // B2 = Tm @ W^T  -> global + stash into ASS
    for (int t = tid; t < 4096; t += 256) {
        int q = t >> 6, r = t & 63;
        float acc = 0.f;
        #pragma unroll 8
        for (int mc = 0; mc < 64; ++mc) acc += Tm[q*64 + mc] * Wl[r*64 + mc];
        g_B2[t] = acc;
        ASS[t] = acc;
    }
    __syncthreads();
    // D_SS = mask .* B2  (in place on ASS)
    for (int t = tid; t < 4096; t += 256) {
        int n = t >> 6, mc = t & 63;
        float mv = (n == mc) ? 1.f : actS[n] * actS[mc];
        ASS[t] *= mv;
    }
    __syncthreads();
    // Tm = W^T @ D_SS
    for (int t = tid; t < 4096; t += 256) {
        int q = t >> 6, mc = t & 63;
        float acc = 0.f;
        #pragma unroll 8
        for (int n = 0; n < 64; ++n) acc += Wl[n*64 + q] * ASS[n*64 + mc];
        Tm[t] = acc;
    }
    __syncthreads();
    // C2 = Tm @ W
    for (int t = tid; t < 4096; t += 256) {
        int q = t >> 6, r = t & 63;
        float acc = 0.f;
        #pragma unroll 8
        for (int mc = 0; mc < 64; ++mc) acc += Tm[q*64 + mc] * Wl[mc*64 + r];
        g_C2[t] = acc;
    }
}

// RA[m][j] = sum_n W[m][n] * A[S[n]][j]
__global__ __launch_bounds__(256) void k_ra(const float* __restrict__ A,
                                            float* __restrict__ ws)
{
    const int b = blockIdx.x;
    const int chunk = blockIdx.y;        // 4 chunks of 128 columns
    float* base = ws + (size_t)b * WS_STRIDE;
    const int* g_S = (const int*)(base + WS_S);
    const float* g_W = base + WS_W;
    float* RA = base + WS_RA;

    __shared__ float Wl[64*64];
    __shared__ int Ssh[64];
    for (int t = threadIdx.x; t < 4096; t += 256) Wl[t] = g_W[t];
    if (threadIdx.x < 64) Ssh[threadIdx.x] = g_S[threadIdx.x];
    __syncthreads();

    const int j = chunk*128 + (threadIdx.x & 127);
    const int mh = threadIdx.x >> 7;     // 0 or 1 -> m half
    float a[64];
    #pragma unroll
    for (int n = 0; n < 64; ++n) a[n] = A[((size_t)b*NDIM + Ssh[n])*NDIM + j];
    for (int m = mh*32; m < mh*32 + 32; ++m) {
        float acc = 0.f;
        #pragma unroll
        for (int n = 0; n < 64; ++n) acc += Wl[m*64 + n] * a[n];
        RA[m*NDIM + j] = acc;
    }
}

// RD[q][j] = sum_n W[n][q] * D[S[n]][j], with D's S-rows built from RA/B2/mask
__global__ __launch_bounds__(256) void k_rd(float* __restrict__ ws)
{
    const int b = blockIdx.x;
    const int chunk = blockIdx.y;
    float* base = ws + (size_t)b * WS_STRIDE;
    const int*   g_posmap = (const int*)(base + WS_PM);
    const int*   g_S  = (const int*)(base + WS_S);
    const float* g_act = base + WS_ACT;
    const float* g_W  = base + WS_W;
    const float* g_B2 = base + WS_B2;
    const float* RA   = base + WS_RA;
    float* RD = base + WS_RD;

    __shared__ float Wl[64*64];
    __shared__ int Ssh[64];
    __shared__ float actS[64];
    for (int t = threadIdx.x; t < 4096; t += 256) Wl[t] = g_W[t];
    if (threadIdx.x < 64) {
        int n = g_S[threadIdx.x];
        Ssh[threadIdx.x] = n;
        actS[threadIdx.x] = g_act[n];
    }
    __syncthreads();

    const int j = chunk*128 + (threadIdx.x & 127);
    const int qh = threadIdx.x >> 7;
    const int pj = g_posmap[j];
    const float actj = g_act[j];
    float d[64];
    #pragma unroll
    for (int n = 0; n < 64; ++n) {
        int i = Ssh[n];
        float mv = (i == j) ? 1.f : actS[n] * actj;
        float v = (pj < 0) ? RA[n*NDIM + j] : g_B2[n*64 + pj];
        d[n] = mv * v;
    }
    for (int q = qh*32; q < qh*32 + 32; ++q) {
        float acc = 0.f;
        #pragma unroll
        for (int n = 0; n < 64; ++n) acc += Wl[n*64 + q] * d[n];
        RD[q*NDIM + j] = acc;
    }
}

// one pass over (b,i,j): write A_rec, right, D
__global__ __launch_bounds__(256) void k_big(const float* __restrict__ A,
                                             const float* __restrict__ ws,
                                             float* __restrict__ out)
{
    const int i = blockIdx.x;
    const int b = blockIdx.y;
    const float* base = ws + (size_t)b * WS_STRIDE;
    const int*   posmap = (const int*)(base + WS_PM);
    const float* act = base + WS_ACT;
    const float* g_W  = base + WS_W;
    const float* g_B2 = base + WS_B2;
    const float* g_C2 = base + WS_C2;
    const float* RA = base + WS_RA;
    const float* RD = base + WS_RD;

    const int pi = posmap[i];
    const float acti = act[i];
    const size_t rowoff = ((size_t)b*NDIM + i)*NDIM;
    const size_t seg = (size_t)BATCH*NDIM*NDIM;
    float* outArec  = out;
    float* outRight = out + seg;
    float* outD     = out + 2*seg;

    for (int j = threadIdx.x; j < NDIM; j += 256) {
        const int pj = posmap[j];
        const float actj = act[j];
        float a;
        if (pi < 0) {
            a = (pj < 0) ? A[rowoff + j] : RA[pj*NDIM + i];
        } else {
            a = (pj < 0) ? RA[pi*NDIM + j] : g_B2[pi*64 + pj];
        }
        const float mv = (i == j) ? 1.f : acti * actj;
        const float dv = a * mv;
        const float rv = (pi >= 0 && pj >= 0) ? g_W[pi*64 + pj]
                                              : ((i == j) ? 1.f : 0.f);
        float arec;
        if (pi < 0) {
            arec = (pj < 0) ? dv : RD[pj*NDIM + i];
        } else {
            arec = (pj < 0) ? RD[pi*NDIM + j] : g_C2[pi*64 + pj];
        }
        outArec[rowoff + j]  = arec;
        outRight[rowoff + j] = rv;
        outD[rowoff + j]     = dv;
    }
}

extern "C" void kernel_launch(void* const* d_in, const int* in_sizes, int n_in,
                              void* d_out, int out_size, void* d_ws, size_t ws_size,
                              hipStream_t stream) {
    const float* A       = (const float*)d_in[0];
    const float* O       = (const float*)d_in[1];
    const int*   indices = (const int*)d_in[2];
    const int*   wavelet = (const int*)d_in[3];
    float* ws  = (float*)d_ws;   // needs ~10.1 MB
    float* out = (float*)d_out;

    k_setup<<<dim3(BATCH), 256, 0, stream>>>(A, O, indices, wavelet, ws);
    k_ra  <<<dim3(BATCH, 4), 256, 0, stream>>>(A, ws);
    k_rd  <<<dim3(BATCH, 4), 256, 0, stream>>>(ws);
    k_big <<<dim3(NDIM, BATCH), 256, 0, stream>>>(A, ws, out);
}

// Round 2
// 224.360 us; speedup vs baseline: 1.1961x; 1.1961x over previous
//
#include <hip/hip_runtime.h>

#define BATCH 32
#define NDIM 512
#define LNUM 8
#define KDIM 8

// per-batch workspace layout (float offsets)
#define WS_PM     0        // int[512]  posmap: node -> pos in S, or -1
#define WS_S      512      // int[64]   S (padded with 0 beyond s)
#define WS_ACT    640      // float[512] active mask (0 if in wavelet set)
#define WS_W      1152     // float[64*64] W (right restricted to SxS; zero-padded)
#define WS_B2     5248     // float[64*64] B2 = W * A_SS * W^T
#define WS_C2     9344     // float[64*64] C2 = W^T * D_SS * W
#define WS_RA     13440    // float[64*512] RA[m][j] = sum_n W[m][n] A[S[n]][j]
#define WS_RD     46208    // float[64*512] RD[q][j] = sum_n W[n][q] D[S[n]][j]
#define WS_STRIDE 78976

// ---------------------------------------------------------------------------
// k_setup: posmap/S/act + serial W build only. No matmuls (moved to k_b2/k_c2).
__global__ __launch_bounds__(256) void k_setup(
    const float* __restrict__ O,
    const int* __restrict__ indices, const int* __restrict__ wavelet,
    float* __restrict__ ws)
{
    const int b = blockIdx.x;
    const int tid = threadIdx.x;
    float* base = ws + (size_t)b * WS_STRIDE;
    int*   g_posmap = (int*)(base + WS_PM);
    int*   g_S      = (int*)(base + WS_S);
    float* g_act    = base + WS_ACT;
    float* g_W      = base + WS_W;

    __shared__ float Wl[64*65];          // stride 65: conflict-free columns
    __shared__ float tmp[KDIM*64];
    __shared__ float Oall[LNUM*KDIM*KDIM];
    __shared__ int   idxsh[64];
    __shared__ int   Ssh[64];
    __shared__ int   pml[NDIM];
    __shared__ float actl[NDIM];
    __shared__ int   prow[KDIM];
    __shared__ int   s_sh;

    // prefetch everything global up-front (coalesced)
    for (int t = tid; t < LNUM*KDIM*KDIM; t += 256) {
        int l = t >> 6, k = t & 63;
        Oall[t] = O[((size_t)l*BATCH + b)*(KDIM*KDIM) + k];
    }
    if (tid < 64) idxsh[tid] = indices[b*64 + tid];
    for (int n = tid; n < NDIM; n += 256) { pml[n] = -1; actl[n] = 1.f; }
    __syncthreads();

    // build S (first-occurrence order) + posmap via wave-0 ballot
    if (tid < 64) {
        int n = idxsh[tid];
        bool first = true;
        for (int t = 0; t < tid; ++t) if (idxsh[t] == n) first = false;
        unsigned long long m = __ballot(first);
        int rank = __popcll(m & ((1ull << tid) - 1ull));
        if (first) { pml[n] = rank; Ssh[rank] = n; }
        if (tid == 0) s_sh = (int)__popcll(m);
    }
    if (tid >= 64 && tid < 64 + LNUM) {
        actl[wavelet[b*LNUM + (tid - 64)]] = 0.f;
    }
    __syncthreads();
    const int s = s_sh;
    if (tid < 64 && tid >= s) Ssh[tid] = 0;   // safe padding
    __syncthreads();

    for (int n = tid; n < NDIM; n += 256) { g_posmap[n] = pml[n]; g_act[n] = actl[n]; }
    if (tid < 64) g_S[tid] = Ssh[tid];

    // W = I_s (zero padded)
    for (int t = tid; t < 4096; t += 256) {
        int rr = t >> 6, cc = t & 63;
        Wl[rr*65 + cc] = (rr == cc && rr < s) ? 1.f : 0.f;
    }
    __syncthreads();

    // apply L layers: rows prow[i] of W <- sum_j O[i][j] * W[prow[j]]
    for (int l = 0; l < LNUM; ++l) {
        if (tid < KDIM) prow[tid] = pml[idxsh[l*KDIM + tid]];
        __syncthreads();
        for (int t = tid; t < KDIM*64; t += 256) {
            int i = t >> 6, c = t & 63;
            float acc = 0.f;
            #pragma unroll
            for (int j = 0; j < KDIM; ++j)
                acc += Oall[l*64 + i*KDIM + j] * Wl[prow[j]*65 + c];
            tmp[t] = acc;
        }
        __syncthreads();
        for (int t = tid; t < KDIM*64; t += 256) {
            int i = t >> 6, c = t & 63;
            Wl[prow[i]*65 + c] = tmp[t];
        }
        __syncthreads();
    }
    for (int t = tid; t < 4096; t += 256) g_W[t] = Wl[(t >> 6)*65 + (t & 63)];
}

// ---------------------------------------------------------------------------
// RA[m][j] = sum_n W[m][n] * A[S[n]][j]
__global__ __launch_bounds__(256) void k_ra(const float* __restrict__ A,
                                            float* __restrict__ ws)
{
    const int b = blockIdx.x;
    const int chunk = blockIdx.y;        // 4 chunks of 128 columns
    float* base = ws + (size_t)b * WS_STRIDE;
    const int* g_S = (const int*)(base + WS_S);
    const float* g_W = base + WS_W;
    float* RA = base + WS_RA;

    __shared__ float Wl[64*64];
    __shared__ int Ssh[64];
    for (int t = threadIdx.x; t < 4096; t += 256) Wl[t] = g_W[t];
    if (threadIdx.x < 64) Ssh[threadIdx.x] = g_S[threadIdx.x];
    __syncthreads();

    const int j = chunk*128 + (threadIdx.x & 127);
    const int mh = threadIdx.x >> 7;     // 0 or 1 -> m half
    float a[64];
    #pragma unroll
    for (int n = 0; n < 64; ++n) a[n] = A[((size_t)b*NDIM + Ssh[n])*NDIM + j];
    for (int m = mh*32; m < mh*32 + 32; ++m) {
        float acc = 0.f;
        #pragma unroll
        for (int n = 0; n < 64; ++n) acc += Wl[m*64 + n] * a[n];   // Wl broadcast
        RA[m*NDIM + j] = acc;
    }
}

// ---------------------------------------------------------------------------
// B2[q][r] = sum_m RA[q][S[m]] * W[r][m]   (== W A_SS W^T)
__global__ __launch_bounds__(256) void k_b2(float* __restrict__ ws)
{
    const int b = blockIdx.x;
    const int tid = threadIdx.x;
    float* base = ws + (size_t)b * WS_STRIDE;
    const int*   g_S = (const int*)(base + WS_S);
    const float* g_W = base + WS_W;
    const float* RA  = base + WS_RA;
    float* g_B2 = base + WS_B2;

    __shared__ float Wl[64*65];
    __shared__ float RAS[64*65];
    __shared__ int Ssh[64];
    if (tid < 64) Ssh[tid] = g_S[tid];
    for (int t = tid; t < 4096; t += 256)
        Wl[(t >> 6)*65 + (t & 63)] = g_W[t];
    __syncthreads();
    for (int t = tid; t < 4096; t += 256) {
        int q = t >> 6, m = t & 63;
        RAS[q*65 + m] = RA[q*NDIM + Ssh[m]];
    }
    __syncthreads();
    for (int t = tid; t < 4096; t += 256) {
        int q = t >> 6, r = t & 63;
        float acc = 0.f;
        #pragma unroll 8
        for (int m = 0; m < 64; ++m)
            acc += RAS[q*65 + m] * Wl[r*65 + m];   // stride 65: conflict-free
        g_B2[t] = acc;
    }
}

// ---------------------------------------------------------------------------
// RD[q][j] = sum_n W[n][q] * D[S[n]][j], D's S-rows built from RA/B2/mask
__global__ __launch_bounds__(256) void k_rd(float* __restrict__ ws)
{
    const int b = blockIdx.x;
    const int chunk = blockIdx.y;
    float* base = ws + (size_t)b * WS_STRIDE;
    const int*   g_posmap = (const int*)(base + WS_PM);
    const int*   g_S  = (const int*)(base + WS_S);
    const float* g_act = base + WS_ACT;
    const float* g_W  = base + WS_W;
    const float* g_B2 = base + WS_B2;
    const float* RA   = base + WS_RA;
    float* RD = base + WS_RD;

    __shared__ float Wl[64*64];
    __shared__ int Ssh[64];
    __shared__ float actS[64];
    for (int t = threadIdx.x; t < 4096; t += 256) Wl[t] = g_W[t];
    if (threadIdx.x < 64) {
        int n = g_S[threadIdx.x];
        Ssh[threadIdx.x] = n;
        actS[threadIdx.x] = g_act[n];
    }
    __syncthreads();

    const int j = chunk*128 + (threadIdx.x & 127);
    const int qh = threadIdx.x >> 7;
    const int pj = g_posmap[j];
    const float actj = g_act[j];
    float d[64];
    #pragma unroll
    for (int n = 0; n < 64; ++n) {
        int i = Ssh[n];
        float mv = (i == j) ? 1.f : actS[n] * actj;
        float v = (pj < 0) ? RA[n*NDIM + j] : g_B2[n*64 + pj];
        d[n] = mv * v;
    }
    for (int q = qh*32; q < qh*32 + 32; ++q) {
        float acc = 0.f;
        #pragma unroll
        for (int n = 0; n < 64; ++n) acc += Wl[n*64 + q] * d[n];   // broadcast
        RD[q*NDIM + j] = acc;
    }
}

// ---------------------------------------------------------------------------
// C2[q][r] = sum_m RD[q][S[m]] * W[m][r]   (== W^T D_SS W)
__global__ __launch_bounds__(256) void k_c2(float* __restrict__ ws)
{
    const int b = blockIdx.x;
    const int tid = threadIdx.x;
    float* base = ws + (size_t)b * WS_STRIDE;
    const int*   g_S = (const int*)(base + WS_S);
    const float* g_W = base + WS_W;
    const float* RD  = base + WS_RD;
    float* g_C2 = base + WS_C2;

    __shared__ float Wl[64*65];
    __shared__ float RDS[64*65];
    __shared__ int Ssh[64];
    if (tid < 64) Ssh[tid] = g_S[tid];
    for (int t = tid; t < 4096; t += 256)
        Wl[(t >> 6)*65 + (t & 63)] = g_W[t];
    __syncthreads();
    for (int t = tid; t < 4096; t += 256) {
        int q = t >> 6, m = t & 63;
        RDS[q*65 + m] = RD[q*NDIM + Ssh[m]];
    }
    __syncthreads();
    for (int t = tid; t < 4096; t += 256) {
        int q = t >> 6, r = t & 63;
        float acc = 0.f;
        #pragma unroll 8
        for (int m = 0; m < 64; ++m)
            acc += RDS[q*65 + m] * Wl[m*65 + r];   // row-contig: conflict-free
        g_C2[t] = acc;
    }
}

// ---------------------------------------------------------------------------
// one float4-vectorized pass over (b,i,j): write A_rec, right, D
__global__ __launch_bounds__(256) void k_big(const float* __restrict__ A,
                                             const float* __restrict__ ws,
                                             float* __restrict__ out)
{
    const int b = blockIdx.y;
    const int rh = threadIdx.x >> 7;          // 2 rows per block
    const int lane = threadIdx.x & 127;       // 128 float4s per row
    const int i = blockIdx.x*2 + rh;
    const int j0 = lane*4;

    const float* base = ws + (size_t)b * WS_STRIDE;
    const int*   posmap = (const int*)(base + WS_PM);
    const float* act = base + WS_ACT;
    const float* g_W  = base + WS_W;
    const float* g_B2 = base + WS_B2;
    const float* g_C2 = base + WS_C2;
    const float* RA = base + WS_RA;
    const float* RD = base + WS_RD;

    const int pi = posmap[i];
    const float acti = act[i];
    const size_t rowoff = ((size_t)b*NDIM + i)*NDIM;
    const size_t seg = (size_t)BATCH*NDIM*NDIM;

    int4   p4  = ((const int4*)posmap)[lane];
    float4 aj4 = ((const float4*)act)[lane];
    int   pm[4] = {p4.x, p4.y, p4.z, p4.w};
    float aj[4] = {aj4.x, aj4.y, aj4.z, aj4.w};

    float a[4], arec[4], dv[4], rv[4];

    if (pi < 0) {
        float4 v = ((const float4*)(A + rowoff))[lane];
        a[0]=v.x; a[1]=v.y; a[2]=v.z; a[3]=v.w;
        #pragma unroll
        for (int c = 0; c < 4; ++c) {
            int pj = pm[c];
            if (pj >= 0) a[c] = RA[pj*NDIM + i];
            float mv = (i == j0 + c) ? 1.f : acti * aj[c];
            dv[c] = a[c] * mv;
            arec[c] = (pj < 0) ? dv[c] : RD[pj*NDIM + i];
            rv[c] = (i == j0 + c) ? 1.f : 0.f;
        }
    } else {
        float4 v = ((const float4*)(RA + pi*NDIM))[lane];
        float4 w = ((const float4*)(RD + pi*NDIM))[lane];
        a[0]=v.x; a[1]=v.y; a[2]=v.z; a[3]=v.w;
        arec[0]=w.x; arec[1]=w.y; arec[2]=w.z; arec[3]=w.w;
        #pragma unroll
        for (int c = 0; c < 4; ++c) {
            int pj = pm[c];
            if (pj >= 0) {
                a[c]    = g_B2[pi*64 + pj];
                arec[c] = g_C2[pi*64 + pj];
                rv[c]   = g_W[pi*64 + pj];
            } else {
                rv[c] = 0.f;           // i in S, j not in S -> i != j
            }
            float mv = (i == j0 + c) ? 1.f : acti * aj[c];
            dv[c] = a[c] * mv;
        }
    }

    ((float4*)(out + rowoff))[lane]         = make_float4(arec[0], arec[1], arec[2], arec[3]);
    ((float4*)(out + seg + rowoff))[lane]   = make_float4(rv[0], rv[1], rv[2], rv[3]);
    ((float4*)(out + 2*seg + rowoff))[lane] = make_float4(dv[0], dv[1], dv[2], dv[3]);
}

extern "C" void kernel_launch(void* const* d_in, const int* in_sizes, int n_in,
                              void* d_out, int out_size, void* d_ws, size_t ws_size,
                              hipStream_t stream) {
    const float* A       = (const float*)d_in[0];
    const float* O       = (const float*)d_in[1];
    const int*   indices = (const int*)d_in[2];
    const int*   wavelet = (const int*)d_in[3];
    float* ws  = (float*)d_ws;   // needs ~10.1 MB
    float* out = (float*)d_out;

    k_setup<<<dim3(BATCH), 256, 0, stream>>>(O, indices, wavelet, ws);
    k_ra  <<<dim3(BATCH, 4), 256, 0, stream>>>(A, ws);
    k_b2  <<<dim3(BATCH), 256, 0, stream>>>(ws);
    k_rd  <<<dim3(BATCH, 4), 256, 0, stream>>>(ws);
    k_c2  <<<dim3(BATCH), 256, 0, stream>>>(ws);
    k_big <<<dim3(NDIM/2, BATCH), 256, 0, stream>>>(A, ws, out);
}

// Round 3
// 216.413 us; speedup vs baseline: 1.2400x; 1.0367x over previous
//
#include <hip/hip_runtime.h>

#define BATCH 32
#define NDIM 512
#define LNUM 8
#define KDIM 8

// per-batch workspace layout (float offsets)
#define WS_PM     0        // int[512]  posmap: node -> pos in S, or -1
#define WS_S      512      // int[64]   S (padded with 0 beyond s)
#define WS_ACT    640      // float[512] active mask (0 if in wavelet set)
#define WS_W      1152     // float[64*64]
#define WS_B2     5248     // float[64*64] B2 = W A_SS W^T
#define WS_C2     9344     // float[64*64] C2 = W^T D_SS W
#define WS_RA     13440    // float[64*512]
#define WS_RD     46208    // float[64*512]
#define WS_STRIDE 78976

#define LSTR 65            // LDS row stride (odd: conflict-free column reads)
#define RSTR 130           // RA-tile stride (128 cols + pad)

// ---------------------------------------------------------------------------
// Fused per-batch prep: setup + W-build + B2/C2 chain + RA/RD chunk.
// grid (BATCH, 4): each block owns 128 columns; matmul work is redundant
// across the 4 chunk-blocks (cheap) so there is NO cross-block dependency.
__global__ __launch_bounds__(256) void k_prep(
    const float* __restrict__ A, const float* __restrict__ O,
    const int* __restrict__ indices, const int* __restrict__ wavelet,
    float* __restrict__ ws)
{
    const int b = blockIdx.x;
    const int chunk = blockIdx.y;
    const int tid = threadIdx.x;
    float* base = ws + (size_t)b * WS_STRIDE;

    __shared__ float Wl[64*LSTR];
    __shared__ float pool[2*64*LSTR];   // P1 | P2 ; later reused as RAt[64][RSTR]
    __shared__ float B2l[64*LSTR];
    __shared__ int   pml[NDIM];
    __shared__ float actl[NDIM];
    __shared__ float actS[64];
    __shared__ int   idxsh[64];
    __shared__ int   Ssh[64];
    __shared__ int   prow[KDIM];
    __shared__ float Oall[LNUM*KDIM*KDIM];
    __shared__ int   s_sh;
    float* P1 = pool;
    float* P2 = pool + 64*LSTR;
    float* RAt = pool;                  // 64*RSTR == 2*64*LSTR exactly

    // ---- setup ----
    for (int t = tid; t < LNUM*KDIM*KDIM; t += 256) {
        int l = t >> 6, k = t & 63;
        Oall[t] = O[((size_t)l*BATCH + b)*(KDIM*KDIM) + k];
    }
    if (tid < 64) idxsh[tid] = indices[b*64 + tid];
    for (int n = tid; n < NDIM; n += 256) { pml[n] = -1; actl[n] = 1.f; }
    __syncthreads();

    if (tid < 64) {
        int n = idxsh[tid];
        bool first = true;
        for (int t = 0; t < tid; ++t) if (idxsh[t] == n) first = false;
        unsigned long long m = __ballot(first);
        int rank = __popcll(m & ((1ull << tid) - 1ull));
        if (first) { pml[n] = rank; Ssh[rank] = n; }
        if (tid == 0) s_sh = (int)__popcll(m);
    }
    if (tid >= 64 && tid < 64 + LNUM) {
        actl[wavelet[b*LNUM + (tid - 64)]] = 0.f;
    }
    __syncthreads();
    const int s = s_sh;
    if (tid < 64 && tid >= s) Ssh[tid] = 0;
    __syncthreads();
    if (tid < 64) actS[tid] = actl[Ssh[tid]];

    if (chunk == 0) {
        int*   g_posmap = (int*)(base + WS_PM);
        int*   g_S      = (int*)(base + WS_S);
        float* g_act    = base + WS_ACT;
        for (int n = tid; n < NDIM; n += 256) { g_posmap[n] = pml[n]; g_act[n] = actl[n]; }
        if (tid < 64) g_S[tid] = Ssh[tid];
    }

    // ---- W build (serial over L layers; tmp staged in B2l region) ----
    for (int t = tid; t < 4096; t += 256) {
        int rr = t >> 6, cc = t & 63;
        Wl[rr*LSTR + cc] = (rr == cc && rr < s) ? 1.f : 0.f;
    }
    __syncthreads();
    for (int l = 0; l < LNUM; ++l) {
        if (tid < KDIM) prow[tid] = pml[idxsh[l*KDIM + tid]];
        __syncthreads();
        for (int t = tid; t < KDIM*64; t += 256) {
            int i = t >> 6, c = t & 63;
            float acc = 0.f;
            #pragma unroll
            for (int j = 0; j < KDIM; ++j)
                acc += Oall[l*64 + i*KDIM + j] * Wl[prow[j]*LSTR + c];
            B2l[t] = acc;
        }
        __syncthreads();
        for (int t = tid; t < KDIM*64; t += 256) {
            int i = t >> 6, c = t & 63;
            Wl[prow[i]*LSTR + c] = B2l[t];
        }
        __syncthreads();
    }
    if (chunk == 0) {
        float* g_W = base + WS_W;
        for (int t = tid; t < 4096; t += 256) g_W[t] = Wl[(t>>6)*LSTR + (t&63)];
    }

    // ---- gather A_SS -> P1 ----
    for (int t = tid; t < 4096; t += 256) {
        int n = t >> 6, m = t & 63;
        P1[n*LSTR + m] = A[((size_t)b*NDIM + Ssh[n])*NDIM + Ssh[m]];
    }
    __syncthreads();

    const int w = tid >> 6;        // wave id 0..3 -> rows w*16..w*16+15
    const int ln = tid & 63;       // lane
    float acc[16];

    // ---- T = W * A_SS -> P2   (lane = col m; broadcast W) ----
    #pragma unroll
    for (int k = 0; k < 16; ++k) acc[k] = 0.f;
    for (int n = 0; n < 64; ++n) {
        float as = P1[n*LSTR + ln];
        #pragma unroll
        for (int k = 0; k < 16; ++k) acc[k] += Wl[(w*16 + k)*LSTR + n] * as;
    }
    #pragma unroll
    for (int k = 0; k < 16; ++k) P2[(w*16 + k)*LSTR + ln] = acc[k];
    __syncthreads();

    // ---- B2 = T * W^T -> B2l  (lane = col r; vector-read W col, bcast T) ----
    #pragma unroll
    for (int k = 0; k < 16; ++k) acc[k] = 0.f;
    for (int m = 0; m < 64; ++m) {
        float wv = Wl[ln*LSTR + m];
        #pragma unroll
        for (int k = 0; k < 16; ++k) acc[k] += P2[(w*16 + k)*LSTR + m] * wv;
    }
    #pragma unroll
    for (int k = 0; k < 16; ++k) B2l[(w*16 + k)*LSTR + ln] = acc[k];
    __syncthreads();
    if (chunk == 0) {
        float* g_B2 = base + WS_B2;
        for (int t = tid; t < 4096; t += 256) g_B2[t] = B2l[(t>>6)*LSTR + (t&63)];
    }

    // ---- D_SS = mask .* B2 -> P1 ----
    for (int t = tid; t < 4096; t += 256) {
        int n = t >> 6, m = t & 63;
        float mv = (Ssh[n] == Ssh[m]) ? 1.f : actS[n]*actS[m];
        P1[n*LSTR + m] = mv * B2l[n*LSTR + m];
    }
    __syncthreads();

    // ---- T2 = W^T * D_SS -> P2 ----
    #pragma unroll
    for (int k = 0; k < 16; ++k) acc[k] = 0.f;
    for (int n = 0; n < 64; ++n) {
        float dv = P1[n*LSTR + ln];
        #pragma unroll
        for (int k = 0; k < 16; ++k) acc[k] += Wl[n*LSTR + (w*16 + k)] * dv;
    }
    #pragma unroll
    for (int k = 0; k < 16; ++k) P2[(w*16 + k)*LSTR + ln] = acc[k];
    __syncthreads();

    // ---- C2 = T2 * W -> registers -> global (chunk 0 only writes) ----
    #pragma unroll
    for (int k = 0; k < 16; ++k) acc[k] = 0.f;
    for (int m = 0; m < 64; ++m) {
        float wv = Wl[m*LSTR + ln];
        #pragma unroll
        for (int k = 0; k < 16; ++k) acc[k] += P2[(w*16 + k)*LSTR + m] * wv;
    }
    if (chunk == 0) {
        float* g_C2 = base + WS_C2;
        #pragma unroll
        for (int k = 0; k < 16; ++k) g_C2[(w*16 + k)*64 + ln] = acc[k];
    }
    __syncthreads();   // P1/P2 now dead -> reuse as RAt

    // ---- RA for this chunk's 128 columns (stage in RAt + write global) ----
    float* g_RA = base + WS_RA;
    float* g_RD = base + WS_RD;
    const int jl = tid & 127;
    const int j  = chunk*128 + jl;
    const int mh = tid >> 7;            // m/q half
    const int pj = pml[j];
    const float actj = actl[j];

    float a[64];
    #pragma unroll
    for (int n = 0; n < 64; ++n)
        a[n] = A[((size_t)b*NDIM + Ssh[n])*NDIM + j];
    for (int mm = 0; mm < 32; ++mm) {
        int m = mh*32 + mm;
        float r = 0.f;
        #pragma unroll
        for (int n = 0; n < 64; ++n) r += Wl[m*LSTR + n] * a[n];
        RAt[m*RSTR + jl] = r;
        g_RA[m*NDIM + j] = r;
    }
    __syncthreads();

    // ---- RD for this chunk's columns (D's S-rows from RAt/B2l/mask) ----
    float d[64];
    #pragma unroll
    for (int n = 0; n < 64; ++n) {
        float v = (pj < 0) ? RAt[n*RSTR + jl] : B2l[n*LSTR + pj];
        float mv = (Ssh[n] == j) ? 1.f : actS[n]*actj;
        d[n] = mv * v;
    }
    for (int qq = 0; qq < 32; ++qq) {
        int q = mh*32 + qq;
        float r = 0.f;
        #pragma unroll
        for (int n = 0; n < 64; ++n) r += Wl[n*LSTR + q] * d[n];
        g_RD[q*NDIM + j] = r;
    }
}

// ---------------------------------------------------------------------------
// one float4-vectorized pass over (b,i,j): write A_rec, right, D
__global__ __launch_bounds__(256) void k_big(const float* __restrict__ A,
                                             const float* __restrict__ ws,
                                             float* __restrict__ out)
{
    const int b = blockIdx.y;
    const int rh = threadIdx.x >> 7;          // 2 rows per block
    const int lane = threadIdx.x & 127;       // 128 float4s per row
    const int i = blockIdx.x*2 + rh;
    const int j0 = lane*4;

    const float* base = ws + (size_t)b * WS_STRIDE;
    const int*   posmap = (const int*)(base + WS_PM);
    const float* act = base + WS_ACT;
    const float* g_W  = base + WS_W;
    const float* g_B2 = base + WS_B2;
    const float* g_C2 = base + WS_C2;
    const float* RA = base + WS_RA;
    const float* RD = base + WS_RD;

    const int pi = posmap[i];
    const float acti = act[i];
    const size_t rowoff = ((size_t)b*NDIM + i)*NDIM;
    const size_t seg = (size_t)BATCH*NDIM*NDIM;

    int4   p4  = ((const int4*)posmap)[lane];
    float4 aj4 = ((const float4*)act)[lane];
    int   pm[4] = {p4.x, p4.y, p4.z, p4.w};
    float aj[4] = {aj4.x, aj4.y, aj4.z, aj4.w};

    float a[4], arec[4], dv[4], rv[4];

    if (pi < 0) {
        float4 v = ((const float4*)(A + rowoff))[lane];
        a[0]=v.x; a[1]=v.y; a[2]=v.z; a[3]=v.w;
        #pragma unroll
        for (int c = 0; c < 4; ++c) {
            int pj = pm[c];
            if (pj >= 0) a[c] = RA[pj*NDIM + i];
            float mv = (i == j0 + c) ? 1.f : acti * aj[c];
            dv[c] = a[c] * mv;
            arec[c] = (pj < 0) ? dv[c] : RD[pj*NDIM + i];
            rv[c] = (i == j0 + c) ? 1.f : 0.f;
        }
    } else {
        float4 v = ((const float4*)(RA + pi*NDIM))[lane];
        float4 w = ((const float4*)(RD + pi*NDIM))[lane];
        a[0]=v.x; a[1]=v.y; a[2]=v.z; a[3]=v.w;
        arec[0]=w.x; arec[1]=w.y; arec[2]=w.z; arec[3]=w.w;
        #pragma unroll
        for (int c = 0; c < 4; ++c) {
            int pj = pm[c];
            if (pj >= 0) {
                a[c]    = g_B2[pi*64 + pj];
                arec[c] = g_C2[pi*64 + pj];
                rv[c]   = g_W[pi*64 + pj];
            } else {
                rv[c] = 0.f;
            }
            float mv = (i == j0 + c) ? 1.f : acti * aj[c];
            dv[c] = a[c] * mv;
        }
    }

    ((float4*)(out + rowoff))[lane]         = make_float4(arec[0], arec[1], arec[2], arec[3]);
    ((float4*)(out + seg + rowoff))[lane]   = make_float4(rv[0], rv[1], rv[2], rv[3]);
    ((float4*)(out + 2*seg + rowoff))[lane] = make_float4(dv[0], dv[1], dv[2], dv[3]);
}

extern "C" void kernel_launch(void* const* d_in, const int* in_sizes, int n_in,
                              void* d_out, int out_size, void* d_ws, size_t ws_size,
                              hipStream_t stream) {
    const float* A       = (const float*)d_in[0];
    const float* O       = (const float*)d_in[1];
    const int*   indices = (const int*)d_in[2];
    const int*   wavelet = (const int*)d_in[3];
    float* ws  = (float*)d_ws;   // needs ~10.1 MB
    float* out = (float*)d_out;

    k_prep<<<dim3(BATCH, 4), 256, 0, stream>>>(A, O, indices, wavelet, ws);
    k_big <<<dim3(NDIM/2, BATCH), 256, 0, stream>>>(A, ws, out);
}

// Round 4
// 196.691 us; speedup vs baseline: 1.3643x; 1.1003x over previous
//
#include <hip/hip_runtime.h>

#define BATCH 32
#define NDIM 512
#define LNUM 8
#define KDIM 8

// per-batch workspace layout (float offsets)
#define WS_PM     0        // int[512]  posmap: node -> pos in S, or -1
#define WS_S      512      // int[64]   S (padded with 0 beyond s)
#define WS_ACT    640      // float[512] active mask (0 if in wavelet set)
#define WS_W      1152     // float[64*64]
#define WS_B2     5248     // float[64*64] B2 = W A_SS W^T
#define WS_C2     9344     // float[64*64] C2 = W^T D_SS W
#define WS_RA     13440    // float[64*512]
#define WS_RD     46208    // float[64*512]
#define WS_STRIDE 78976

#define LSTR 65            // LDS row stride for 64-wide tiles (conflict-free cols)
#define ASTR 33            // LDS stride for 32-col tiles

// ---------------------------------------------------------------------------
// k_chain: per-batch serial part only (32 blocks).
// setup + W-build + B2/D_SS/C2 chain. ~10 us, latency-bound but small.
__global__ __launch_bounds__(256) void k_chain(
    const float* __restrict__ A, const float* __restrict__ O,
    const int* __restrict__ indices, const int* __restrict__ wavelet,
    float* __restrict__ ws)
{
    const int b = blockIdx.x;
    const int tid = threadIdx.x;
    float* base = ws + (size_t)b * WS_STRIDE;

    __shared__ float Wl[64*LSTR];
    __shared__ float P1[64*LSTR];
    __shared__ float P2[64*LSTR];
    __shared__ float B2l[64*LSTR];
    __shared__ int   pml[NDIM];
    __shared__ float actl[NDIM];
    __shared__ float actS[64];
    __shared__ int   idxsh[64];
    __shared__ int   Ssh[64];
    __shared__ int   prow[KDIM];
    __shared__ float Oall[LNUM*KDIM*KDIM];
    __shared__ int   s_sh;

    // ---- setup ----
    for (int t = tid; t < LNUM*KDIM*KDIM; t += 256) {
        int l = t >> 6, k = t & 63;
        Oall[t] = O[((size_t)l*BATCH + b)*(KDIM*KDIM) + k];
    }
    if (tid < 64) idxsh[tid] = indices[b*64 + tid];
    for (int n = tid; n < NDIM; n += 256) { pml[n] = -1; actl[n] = 1.f; }
    __syncthreads();

    if (tid < 64) {
        int n = idxsh[tid];
        bool first = true;
        for (int t = 0; t < tid; ++t) if (idxsh[t] == n) first = false;
        unsigned long long m = __ballot(first);
        int rank = __popcll(m & ((1ull << tid) - 1ull));
        if (first) { pml[n] = rank; Ssh[rank] = n; }
        if (tid == 0) s_sh = (int)__popcll(m);
    }
    if (tid >= 64 && tid < 64 + LNUM) {
        actl[wavelet[b*LNUM + (tid - 64)]] = 0.f;
    }
    __syncthreads();
    const int s = s_sh;
    if (tid < 64 && tid >= s) Ssh[tid] = 0;
    __syncthreads();
    if (tid < 64) actS[tid] = actl[Ssh[tid]];

    {
        int*   g_posmap = (int*)(base + WS_PM);
        int*   g_S      = (int*)(base + WS_S);
        float* g_act    = base + WS_ACT;
        for (int n = tid; n < NDIM; n += 256) { g_posmap[n] = pml[n]; g_act[n] = actl[n]; }
        if (tid < 64) g_S[tid] = Ssh[tid];
    }

    // ---- W build (serial over L layers; tmp staged in B2l region) ----
    for (int t = tid; t < 4096; t += 256) {
        int rr = t >> 6, cc = t & 63;
        Wl[rr*LSTR + cc] = (rr == cc && rr < s) ? 1.f : 0.f;
    }
    __syncthreads();
    for (int l = 0; l < LNUM; ++l) {
        if (tid < KDIM) prow[tid] = pml[idxsh[l*KDIM + tid]];
        __syncthreads();
        for (int t = tid; t < KDIM*64; t += 256) {
            int i = t >> 6, c = t & 63;
            float acc = 0.f;
            #pragma unroll
            for (int j = 0; j < KDIM; ++j)
                acc += Oall[l*64 + i*KDIM + j] * Wl[prow[j]*LSTR + c];
            B2l[t] = acc;
        }
        __syncthreads();
        for (int t = tid; t < KDIM*64; t += 256) {
            int i = t >> 6, c = t & 63;
            Wl[prow[i]*LSTR + c] = B2l[t];
        }
        __syncthreads();
    }
    {
        float* g_W = base + WS_W;
        for (int t = tid; t < 4096; t += 256) g_W[t] = Wl[(t>>6)*LSTR + (t&63)];
    }

    // ---- gather A_SS -> P1 ----
    for (int t = tid; t < 4096; t += 256) {
        int n = t >> 6, m = t & 63;
        P1[n*LSTR + m] = A[((size_t)b*NDIM + Ssh[n])*NDIM + Ssh[m]];
    }
    __syncthreads();

    const int w = tid >> 6;        // wave id 0..3 -> rows w*16..w*16+15
    const int ln = tid & 63;       // lane
    float acc[16];

    // ---- T = W * A_SS -> P2 ----
    #pragma unroll
    for (int k = 0; k < 16; ++k) acc[k] = 0.f;
    for (int n = 0; n < 64; ++n) {
        float as = P1[n*LSTR + ln];
        #pragma unroll
        for (int k = 0; k < 16; ++k) acc[k] += Wl[(w*16 + k)*LSTR + n] * as;
    }
    #pragma unroll
    for (int k = 0; k < 16; ++k) P2[(w*16 + k)*LSTR + ln] = acc[k];
    __syncthreads();

    // ---- B2 = T * W^T -> B2l + global ----
    #pragma unroll
    for (int k = 0; k < 16; ++k) acc[k] = 0.f;
    for (int m = 0; m < 64; ++m) {
        float wv = Wl[ln*LSTR + m];
        #pragma unroll
        for (int k = 0; k < 16; ++k) acc[k] += P2[(w*16 + k)*LSTR + m] * wv;
    }
    #pragma unroll
    for (int k = 0; k < 16; ++k) B2l[(w*16 + k)*LSTR + ln] = acc[k];
    __syncthreads();
    {
        float* g_B2 = base + WS_B2;
        for (int t = tid; t < 4096; t += 256) g_B2[t] = B2l[(t>>6)*LSTR + (t&63)];
    }

    // ---- D_SS = mask .* B2 -> P1 ----
    for (int t = tid; t < 4096; t += 256) {
        int n = t >> 6, m = t & 63;
        float mv = (Ssh[n] == Ssh[m]) ? 1.f : actS[n]*actS[m];
        P1[n*LSTR + m] = mv * B2l[n*LSTR + m];
    }
    __syncthreads();

    // ---- T2 = W^T * D_SS -> P2 ----
    #pragma unroll
    for (int k = 0; k < 16; ++k) acc[k] = 0.f;
    for (int n = 0; n < 64; ++n) {
        float dv = P1[n*LSTR + ln];
        #pragma unroll
        for (int k = 0; k < 16; ++k) acc[k] += Wl[n*LSTR + (w*16 + k)] * dv;
    }
    #pragma unroll
    for (int k = 0; k < 16; ++k) P2[(w*16 + k)*LSTR + ln] = acc[k];
    __syncthreads();

    // ---- C2 = T2 * W -> global ----
    #pragma unroll
    for (int k = 0; k < 16; ++k) acc[k] = 0.f;
    for (int m = 0; m < 64; ++m) {
        float wv = Wl[m*LSTR + ln];
        #pragma unroll
        for (int k = 0; k < 16; ++k) acc[k] += P2[(w*16 + k)*LSTR + m] * wv;
    }
    {
        float* g_C2 = base + WS_C2;
        #pragma unroll
        for (int k = 0; k < 16; ++k) g_C2[(w*16 + k)*64 + ln] = acc[k];
    }
}

// ---------------------------------------------------------------------------
// k_rard: RA + RD for 32-column chunks. grid (BATCH, 16) = 512 blocks.
// S-columns of RA/RD are never consumed by k_big (overwritten by B2/C2),
// so no pj branch and no B2 tile needed.
__global__ __launch_bounds__(256) void k_rard(const float* __restrict__ A,
                                              float* __restrict__ ws)
{
    const int b = blockIdx.x;
    const int j0 = blockIdx.y * 32;
    const int tid = threadIdx.x;
    float* base = ws + (size_t)b * WS_STRIDE;
    const int*   g_S   = (const int*)(base + WS_S);
    const float* g_act = base + WS_ACT;
    const float* g_W   = base + WS_W;
    float* g_RA = base + WS_RA;
    float* g_RD = base + WS_RD;

    __shared__ float Wl[64*LSTR];      // 16.6 KB
    __shared__ float AS[64*ASTR];      // 8.4 KB
    __shared__ float RAt[64*ASTR];     // 8.4 KB
    __shared__ int   Ssh[64];
    __shared__ float actS[64];
    __shared__ float actc[32];

    for (int t = tid; t < 4096; t += 256)
        Wl[(t>>6)*LSTR + (t&63)] = g_W[t];
    if (tid < 64) {
        int n = g_S[tid];
        Ssh[tid] = n;
        actS[tid] = g_act[n];
    }
    if (tid >= 64 && tid < 96) actc[tid-64] = g_act[j0 + (tid-64)];
    __syncthreads();

    // gather A_S tile: AS[n][c] = A[b][S[n]][j0+c]
    for (int t = tid; t < 2048; t += 256) {
        int n = t >> 5, c = t & 31;
        AS[n*ASTR + c] = A[((size_t)b*NDIM + Ssh[n])*NDIM + j0 + c];
    }
    __syncthreads();

    const int c = tid & 31;        // column within chunk
    const int g = tid >> 5;        // m-group 0..7 -> rows g*8..g*8+7
    float acc[8];

    // ---- RA[m][j] = sum_n W[m][n] * AS[n][c] ----
    #pragma unroll
    for (int k = 0; k < 8; ++k) acc[k] = 0.f;
    for (int n = 0; n < 64; ++n) {
        float av = AS[n*ASTR + c];
        #pragma unroll
        for (int k = 0; k < 8; ++k) acc[k] += Wl[(g*8 + k)*LSTR + n] * av;
    }
    #pragma unroll
    for (int k = 0; k < 8; ++k) {
        RAt[(g*8 + k)*ASTR + c] = acc[k];
        g_RA[(g*8 + k)*NDIM + j0 + c] = acc[k];
    }
    __syncthreads();

    // ---- RD[q][j] = sum_n W[n][q] * actS[n]*actj * RAt[n][c] ----
    const float actj = actc[c];
    #pragma unroll
    for (int k = 0; k < 8; ++k) acc[k] = 0.f;
    for (int n = 0; n < 64; ++n) {
        float dv = actS[n] * actj * RAt[n*ASTR + c];
        #pragma unroll
        for (int k = 0; k < 8; ++k) acc[k] += Wl[n*LSTR + g*8 + k] * dv;
    }
    #pragma unroll
    for (int k = 0; k < 8; ++k)
        g_RD[(g*8 + k)*NDIM + j0 + c] = acc[k];
}

// ---------------------------------------------------------------------------
// one float4-vectorized pass over (b,i,j): write A_rec, right, D
__global__ __launch_bounds__(256) void k_big(const float* __restrict__ A,
                                             const float* __restrict__ ws,
                                             float* __restrict__ out)
{
    const int b = blockIdx.y;
    const int rh = threadIdx.x >> 7;          // 2 rows per block
    const int lane = threadIdx.x & 127;       // 128 float4s per row
    const int i = blockIdx.x*2 + rh;
    const int j0 = lane*4;

    const float* base = ws + (size_t)b * WS_STRIDE;
    const int*   posmap = (const int*)(base + WS_PM);
    const float* act = base + WS_ACT;
    const float* g_W  = base + WS_W;
    const float* g_B2 = base + WS_B2;
    const float* g_C2 = base + WS_C2;
    const float* RA = base + WS_RA;
    const float* RD = base + WS_RD;

    const int pi = posmap[i];
    const float acti = act[i];
    const size_t rowoff = ((size_t)b*NDIM + i)*NDIM;
    const size_t seg = (size_t)BATCH*NDIM*NDIM;

    int4   p4  = ((const int4*)posmap)[lane];
    float4 aj4 = ((const float4*)act)[lane];
    int   pm[4] = {p4.x, p4.y, p4.z, p4.w};
    float aj[4] = {aj4.x, aj4.y, aj4.z, aj4.w};

    float a[4], arec[4], dv[4], rv[4];

    if (pi < 0) {
        float4 v = ((const float4*)(A + rowoff))[lane];
        a[0]=v.x; a[1]=v.y; a[2]=v.z; a[3]=v.w;
        #pragma unroll
        for (int c = 0; c < 4; ++c) {
            int pj = pm[c];
            if (pj >= 0) a[c] = RA[pj*NDIM + i];
            float mv = (i == j0 + c) ? 1.f : acti * aj[c];
            dv[c] = a[c] * mv;
            arec[c] = (pj < 0) ? dv[c] : RD[pj*NDIM + i];
            rv[c] = (i == j0 + c) ? 1.f : 0.f;
        }
    } else {
        float4 v = ((const float4*)(RA + pi*NDIM))[lane];
        float4 w = ((const float4*)(RD + pi*NDIM))[lane];
        a[0]=v.x; a[1]=v.y; a[2]=v.z; a[3]=v.w;
        arec[0]=w.x; arec[1]=w.y; arec[2]=w.z; arec[3]=w.w;
        #pragma unroll
        for (int c = 0; c < 4; ++c) {
            int pj = pm[c];
            if (pj >= 0) {
                a[c]    = g_B2[pi*64 + pj];
                arec[c] = g_C2[pi*64 + pj];
                rv[c]   = g_W[pi*64 + pj];
            } else {
                rv[c] = 0.f;
            }
            float mv = (i == j0 + c) ? 1.f : acti * aj[c];
            dv[c] = a[c] * mv;
        }
    }

    ((float4*)(out + rowoff))[lane]         = make_float4(arec[0], arec[1], arec[2], arec[3]);
    ((float4*)(out + seg + rowoff))[lane]   = make_float4(rv[0], rv[1], rv[2], rv[3]);
    ((float4*)(out + 2*seg + rowoff))[lane] = make_float4(dv[0], dv[1], dv[2], dv[3]);
}

extern "C" void kernel_launch(void* const* d_in, const int* in_sizes, int n_in,
                              void* d_out, int out_size, void* d_ws, size_t ws_size,
                              hipStream_t stream) {
    const float* A       = (const float*)d_in[0];
    const float* O       = (const float*)d_in[1];
    const int*   indices = (const int*)d_in[2];
    const int*   wavelet = (const int*)d_in[3];
    float* ws  = (float*)d_ws;   // needs ~10.1 MB
    float* out = (float*)d_out;

    k_chain<<<dim3(BATCH), 256, 0, stream>>>(A, O, indices, wavelet, ws);
    k_rard <<<dim3(BATCH, 16), 256, 0, stream>>>(A, ws);
    k_big  <<<dim3(NDIM/2, BATCH), 256, 0, stream>>>(A, ws, out);
}